// Round 2
// baseline (670.246 us; speedup 1.0000x reference)
//
#include <hip/hip_runtime.h>
#include <math.h>

#define V      128000
#define BEAM   3
#define HIST   16

// flat float32 output offsets (tuple concat order)
#define O_KV   0
#define O_IDX  100663296                 // 32*3*8*1024*128
#define O_SAVE (O_IDX + BEAM)            // +3
#define O_RP   (O_SAVE + BEAM*(HIST+1))  // +51
#define O_PROB (O_RP + BEAM*V)           // +384000
#define O_MAX  (O_PROB + BEAM)

typedef float f4 __attribute__((ext_vector_type(4)));

__device__ __forceinline__ void ins3(float v, int idx,
    float& v0, int& i0, float& v1, int& i1, float& v2, int& i2) {
  if (v > v0)      { v2=v1; i2=i1; v1=v0; i1=i0; v0=v; i0=idx; }
  else if (v > v1) { v2=v1; i2=i1; v1=v;  i1=idx; }
  else if (v > v2) { v2=v;  i2=idx; }
}

// ---------------- phase A: single-block top3 + log_softmax denom -------------
// 1024 threads (16 waves) on one CU stream 512 KB; online softmax + top3.
__global__ __launch_bounds__(1024) void topk_kernel(const float* __restrict__ logits,
                                                    const int* __restrict__ save_id,
                                                    float* __restrict__ out,
                                                    int* __restrict__ ws_idx) {
  const int t = threadIdx.x;
  float m = -INFINITY, s = 0.f;
  float v0 = -INFINITY, v1 = -INFINITY, v2 = -INFINITY;
  int   i0 = 0, i1 = 0, i2 = 0;

  for (int k = t; k < 32000; k += 1024) {       // float4 index
    const f4 x4 = ((const f4*)logits)[k];
    const int base = k << 2;
#pragma unroll
    for (int j = 0; j < 4; ++j) {
      const float x  = x4[j];
      const float nm = fmaxf(m, x);
      s = s * __expf(m - nm) + __expf(x - nm);
      m = nm;
      ins3(x, base + j, v0, i0, v1, i1, v2, i2);
    }
  }

  const int lane = t & 63;
#pragma unroll
  for (int d = 32; d >= 1; d >>= 1) {
    float om  = __shfl_down(m,  d, 64);
    float os  = __shfl_down(s,  d, 64);
    float ov0 = __shfl_down(v0, d, 64); int oi0 = __shfl_down(i0, d, 64);
    float ov1 = __shfl_down(v1, d, 64); int oi1 = __shfl_down(i1, d, 64);
    float ov2 = __shfl_down(v2, d, 64); int oi2 = __shfl_down(i2, d, 64);
    if (lane + d < 64) {                 // guard: never merge wrapped/self data
      const float nm = fmaxf(m, om);
      s = s * __expf(m - nm) + os * __expf(om - nm);
      m = nm;
      ins3(ov0, oi0, v0, i0, v1, i1, v2, i2);
      ins3(ov1, oi1, v0, i0, v1, i1, v2, i2);
      ins3(ov2, oi2, v0, i0, v1, i1, v2, i2);
    }
  }

  __shared__ float sm[16][8];
  __shared__ float res[BEAM];
  const int wave = t >> 6;
  if (lane == 0) {
    sm[wave][0] = m;  sm[wave][1] = s;
    sm[wave][2] = v0; sm[wave][3] = v1; sm[wave][4] = v2;
    sm[wave][5] = __int_as_float(i0);
    sm[wave][6] = __int_as_float(i1);
    sm[wave][7] = __int_as_float(i2);
  }
  __syncthreads();
  if (t == 0) {
#pragma unroll
    for (int w = 1; w < 16; ++w) {
      const float om = sm[w][0], os = sm[w][1];
      const float nm = fmaxf(m, om);
      s = s * __expf(m - nm) + os * __expf(om - nm);
      m = nm;
      ins3(sm[w][2], __float_as_int(sm[w][5]), v0, i0, v1, i1, v2, i2);
      ins3(sm[w][3], __float_as_int(sm[w][6]), v0, i0, v1, i1, v2, i2);
      ins3(sm[w][4], __float_as_int(sm[w][7]), v0, i0, v1, i1, v2, i2);
    }
    const float logZ = m + logf(s);
    out[O_IDX + 0] = (float)i0;
    out[O_IDX + 1] = (float)i1;
    out[O_IDX + 2] = (float)i2;
    out[O_PROB + 0] = v0 - logZ;
    out[O_PROB + 1] = v1 - logZ;
    out[O_PROB + 2] = v2 - logZ;
    out[O_MAX] = (float)i0;
    ws_idx[0] = i0; ws_idx[1] = i1; ws_idx[2] = i2;
    res[0] = (float)i0; res[1] = (float)i1; res[2] = (float)i2;
  }
  __syncthreads();
  if (t < BEAM * (HIST + 1)) {             // 51 elements of concat(save_id, idx)
    const int b = t / (HIST + 1);
    const int j = t - b * (HIST + 1);
    out[O_SAVE + t] = (j < HIST) ? (float)save_id[b * HIST + j] : res[b];
  }
}

// ---------------- phase B: KV beam-tile (read-once, write-3x) + penalty ------
// kv: 32 chunks of 2^18 float4; each kv block handles 1024 float4 (4/thread).
#define RP_BLOCKS 375                      // 375*256 float4 = 3*128000 floats
#define KV_BLOCKS 8192                     // 8192*1024 = 2^23 src float4

__global__ __launch_bounds__(256) void kv_penalty(const f4* __restrict__ kv,
                                                  const float* __restrict__ rp,
                                                  const float* __restrict__ penv,
                                                  const int* __restrict__ ws_idx,
                                                  f4* __restrict__ kv_out,
                                                  float* __restrict__ rp_out) {
  const int b = blockIdx.x;
  if (b >= RP_BLOCKS) {
    const int kb    = b - RP_BLOCKS;            // 0..8191
    const int chunk = kb >> 8;                  // 256 blocks per chunk
    const int off0  = ((kb & 255) << 10) + threadIdx.x;   // float4 units in chunk
    const f4* __restrict__ src = kv + ((long)chunk << 18);
    f4* __restrict__ dst = kv_out + ((long)(chunk * 3) << 18);

    f4 a0 = __builtin_nontemporal_load(src + off0);
    f4 a1 = __builtin_nontemporal_load(src + off0 + 256);
    f4 a2 = __builtin_nontemporal_load(src + off0 + 512);
    f4 a3 = __builtin_nontemporal_load(src + off0 + 768);

#pragma unroll
    for (int r = 0; r < 3; ++r) {
      f4* d = dst + ((long)r << 18);
      __builtin_nontemporal_store(a0, d + off0);
      __builtin_nontemporal_store(a1, d + off0 + 256);
      __builtin_nontemporal_store(a2, d + off0 + 512);
      __builtin_nontemporal_store(a3, d + off0 + 768);
    }
  } else {
    const int i   = (b << 8) | threadIdx.x;     // float4 idx 0..95999
    const int row = i / 32000;                  // beam row
    const int off = i - row * 32000;
    f4 v = ((const f4*)(rp + row * V))[off];
    const int tgt = ws_idx[row];
    const int vb  = off << 2;
    if (tgt >= vb && tgt < vb + 4) {
      v[tgt - vb] *= penv[0];
    }
    // O_RP is only 8B-aligned in the flat output -> float2 stores
    float2* d = (float2*)(rp_out + row * V) + off * 2;
    d[0] = make_float2(v[0], v[1]);
    d[1] = make_float2(v[2], v[3]);
  }
}

extern "C" void kernel_launch(void* const* d_in, const int* in_sizes, int n_in,
                              void* d_out, int out_size, void* d_ws, size_t ws_size,
                              hipStream_t stream) {
  const float* kv      = (const float*)d_in[0];
  const float* logits  = (const float*)d_in[1];
  const int*   save_id = (const int*)d_in[2];
  const float* rp      = (const float*)d_in[3];
  const float* penv    = (const float*)d_in[4];
  float* out = (float*)d_out;
  int* ws_idx = (int*)d_ws;

  topk_kernel<<<1, 1024, 0, stream>>>(logits, save_id, out, ws_idx);
  kv_penalty<<<RP_BLOCKS + KV_BLOCKS, 256, 0, stream>>>(
      (const f4*)kv, rp, penv, ws_idx, (f4*)(out + O_KV), out + O_RP);
}